// Round 10
// baseline (98.554 us; speedup 1.0000x reference)
//
#include <hip/hip_runtime.h>
#include <hip/hip_bf16.h>

// SpiralDeblock: B=8, N_IN=7056, N_UP=28224, SEQ=9, CIN=64, COUT=32
namespace {
constexpr int kB    = 8;
constexpr int kNIn  = 7056;
constexpr int kNUp  = 28224;
constexpr int kSeq  = 9;
constexpr int kCin  = 64;
constexpr int kCout = 32;
constexpr int kE    = 3 * kNUp;          // 84672
constexpr int kMRows = kB * kNUp;        // 225792
constexpr int kTilesPerB = kNUp / 16;    // 1764 (exact -> tiles never straddle batches)
constexpr int kWFragN = 18 * 2 * 64 * 8; // 18432 bf16 values (36,864 B)
constexpr int kCap   = 24;               // bucket capacity; P(overflow) ~ 6e-10 at Poisson(3)

// ws layout (bytes), 16B-aligned
constexpr size_t kOffPool   = 0;                          // bf16 pooled: 28,901,376
constexpr size_t kOffWfrag  = 28901376;                   // 36,864
constexpr size_t kOffCur    = kOffWfrag + 36864;          // 112,896
constexpr size_t kOffBucket = kOffCur + 112896;           // N_UP*24*8 = 5,419,008
}

typedef __attribute__((ext_vector_type(8))) short short8;
typedef __attribute__((ext_vector_type(4))) float f32x4;

__device__ __forceinline__ unsigned short f32_to_bf16(float f) {  // RNE
    unsigned int u = __float_as_uint(f);
    u += 0x7fffu + ((u >> 16) & 1u);
    return (unsigned short)(u >> 16);
}

// --- zero cursor (graph-safe, ~1 us) --------------------------------------
__global__ __launch_bounds__(256) void zero_kernel(int* __restrict__ cursor) {
    int i = blockIdx.x * 256 + threadIdx.x;
    if (i < kNUp) cursor[i] = 0;
}

// --- merged prep: blocks [0,72) transpose W to fragment order; blocks [72,...) bucket edges
__global__ __launch_bounds__(256) void prep_kernel(const float* __restrict__ W,
                                                   unsigned short* __restrict__ wfrag,
                                                   const int* __restrict__ row,
                                                   const int* __restrict__ col,
                                                   const float* __restrict__ val,
                                                   int* __restrict__ cursor,
                                                   uint2* __restrict__ bucket) {
    int bid = blockIdx.x;
    if (bid < kWFragN / 256) {
        int i  = bid * 256 + threadIdx.x;
        int j  = i & 7;
        int l  = (i >> 3) & 63;
        int ct = (i >> 9) & 1;
        int ks = i >> 10;                            // 0..17
        int k  = ks * 32 + (l >> 4) * 8 + j;
        int o  = ct * 16 + (l & 15);
        wfrag[i] = f32_to_bf16(W[k * kCout + o]);
    } else {
        int e = (bid - kWFragN / 256) * 256 + threadIdx.x;
        if (e >= kE) return;
        int r = row[e];
        int slot = atomicAdd(&cursor[r], 1);
        if ((unsigned)slot < (unsigned)kCap)
            bucket[(size_t)r * kCap + slot] = make_uint2((unsigned)col[e], __float_as_uint(val[e]));
    }
}

// --- pooled[b,r,c] = sum_{edges of r} x[b,col,c]*val, stored bf16 ---------
// MEASUREMENT ROUND: this kernel is launched TWICE (idempotent: identical
// writes both times). Delta vs round 9's 76.3 us == this kernel's duration,
// which the poison-fill-flooded top-5 cannot show us directly.
// b = blockIdx&7 keeps the round-9 XCD affinity (one 1.8 MB x-slice per XCD).
__global__ __launch_bounds__(256) void pool_gather(const float* __restrict__ x,
                                                   const int* __restrict__ cursor,
                                                   const uint2* __restrict__ bucket,
                                                   unsigned short* __restrict__ poolb) {
    int t  = threadIdx.x;
    int c4 = t & 15;                                 // float4 chunk within row
    int b  = blockIdx.x & 7;                         // batch -> XCD (round-robin)
    int rb = blockIdx.x >> 3;                        // row-block 0..1763
    int r  = rb * 16 + (t >> 4);                     // < N_UP
    int n  = min(cursor[r], kCap);
    const uint2* bk = bucket + (size_t)r * kCap;
    const float* xb = x + (size_t)b * kNIn * kCin + (size_t)c4 * 4;

    f32x4 acc = {0.f, 0.f, 0.f, 0.f};

#pragma unroll
    for (int p = 0; p < 4; ++p) {                    // pairs (0,1),(2,3),(4,5),(6,7)
        if (2 * p < n) {
            uint4 q = *reinterpret_cast<const uint4*>(bk + 2 * p);
            unsigned c0 = min(q.x, (unsigned)(kNIn - 1));
            float    v0 = __uint_as_float(q.y);
            unsigned c1 = min(q.z, (unsigned)(kNIn - 1));
            float    v1 = (2 * p + 1 < n) ? __uint_as_float(q.w) : 0.f;
            f32x4 xv0 = *reinterpret_cast<const f32x4*>(xb + (size_t)c0 * kCin);
            f32x4 xv1 = *reinterpret_cast<const f32x4*>(xb + (size_t)c1 * kCin);
#pragma unroll
            for (int j = 0; j < 4; ++j)
                acc[j] = fmaf(xv1[j], v1, fmaf(xv0[j], v0, acc[j]));
        }
    }
    for (int k = 8; k < n; ++k) {                    // rare tail (P ~ 0.4%)
        uint2 ev = bk[k];
        float v = __uint_as_float(ev.y);
        f32x4 xv = *reinterpret_cast<const f32x4*>(xb + (size_t)ev.x * kCin);
#pragma unroll
        for (int j = 0; j < 4; ++j)
            acc[j] = fmaf(xv[j], v, acc[j]);
    }

    ushort4 o;
    o.x = f32_to_bf16(acc[0]);
    o.y = f32_to_bf16(acc[1]);
    o.z = f32_to_bf16(acc[2]);
    o.w = f32_to_bf16(acc[3]);
    *reinterpret_cast<ushort4*>(poolb + ((size_t)b * kNUp + r) * kCin + c4 * 4) = o;
}

// --- MFMA GEMM: out[R,o] = relu(sum_f spiral[R,f]*W[f,o] + bias[o]) -------
// 4 waves/block, 1 16-row M-tile per wave. W fragments staged in LDS (36,864 B,
// 4 blocks/CU). All 9 idx + 18 A-fragment loads issued BEFORE __syncthreads():
// barrier fence keeps them hoisted, vmcnt-drain hides latency under LDS fill.
// XCD chunk swizzle: 441 consecutive work-ids = one batch (3.6 MB < 4 MiB L2/XCD).
__global__ __launch_bounds__(256) void gemm_mfma(const unsigned short* __restrict__ poolb,
                                                 const unsigned short* __restrict__ wfrag,
                                                 const float* __restrict__ bias,
                                                 const int* __restrict__ indices,
                                                 float* __restrict__ out) {
    __shared__ short8 Bs[18 * 2 * 64];               // 2304 short8 = 36,864 B
    int t = threadIdx.x;
    const short8* wf = (const short8*)wfrag;
#pragma unroll
    for (int i = 0; i < 9; ++i)                      // coalesced b128 fill
        Bs[i * 256 + t] = wf[i * 256 + t];

    int l = t & 63;
    int w = t >> 6;
    int bid = blockIdx.x;
    int wk = (bid & 7) * (gridDim.x >> 3) + (bid >> 3);  // grid 3528 = 8*441
    int mtile = wk * 4 + w;
    int m  = l & 15;
    int kg = l >> 4;
    int b  = mtile / kTilesPerB;
    int nn = (mtile - b * kTilesPerB) * 16 + m;
    const unsigned short* pb = poolb + (size_t)b * kNUp * kCin;

    int idxs[kSeq];
#pragma unroll
    for (int s = 0; s < kSeq; ++s) idxs[s] = indices[nn * kSeq + s];

    short8 A0[kSeq], A1[kSeq];
#pragma unroll
    for (int s = 0; s < kSeq; ++s) {
        const short8* arow = (const short8*)(pb + (size_t)idxs[s] * kCin);
        A0[s] = arow[kg];                            // channels 0..31, this lane's 16B
        A1[s] = arow[4 + kg];                        // channels 32..63
    }
    float bs0 = bias[m];
    float bs1 = bias[16 + m];

    __syncthreads();                                 // Bs ready; A loads drained here

    f32x4 acc0 = {0.f, 0.f, 0.f, 0.f};
    f32x4 acc1 = {0.f, 0.f, 0.f, 0.f};
#pragma unroll
    for (int s = 0; s < kSeq; ++s) {
        short8 b00 = Bs[((s * 2 + 0) * 2 + 0) * 64 + l];
        short8 b01 = Bs[((s * 2 + 0) * 2 + 1) * 64 + l];
        short8 b10 = Bs[((s * 2 + 1) * 2 + 0) * 64 + l];
        short8 b11 = Bs[((s * 2 + 1) * 2 + 1) * 64 + l];
        acc0 = __builtin_amdgcn_mfma_f32_16x16x32_bf16(A0[s], b00, acc0, 0, 0, 0);
        acc1 = __builtin_amdgcn_mfma_f32_16x16x32_bf16(A0[s], b01, acc1, 0, 0, 0);
        acc0 = __builtin_amdgcn_mfma_f32_16x16x32_bf16(A1[s], b10, acc0, 0, 0, 0);
        acc1 = __builtin_amdgcn_mfma_f32_16x16x32_bf16(A1[s], b11, acc1, 0, 0, 0);
    }

    int orow0 = mtile * 16 + kg * 4;
#pragma unroll
    for (int r = 0; r < 4; ++r) {
        size_t orow = (size_t)(orow0 + r) * kCout;
        out[orow + m]      = fmaxf(acc0[r] + bs0, 0.f);
        out[orow + 16 + m] = fmaxf(acc1[r] + bs1, 0.f);
    }
}

extern "C" void kernel_launch(void* const* d_in, const int* in_sizes, int n_in,
                              void* d_out, int out_size, void* d_ws, size_t ws_size,
                              hipStream_t stream) {
    const float* x    = (const float*)d_in[0];
    const float* val  = (const float*)d_in[1];
    const float* W    = (const float*)d_in[2];
    const float* bias = (const float*)d_in[3];
    const int* row     = (const int*)d_in[4];
    const int* col     = (const int*)d_in[5];
    const int* indices = (const int*)d_in[6];
    float* out = (float*)d_out;

    char* wsb = (char*)d_ws;
    unsigned short* poolb = (unsigned short*)(wsb + kOffPool);
    unsigned short* wfrag = (unsigned short*)(wsb + kOffWfrag);
    int* cursor  = (int*)(wsb + kOffCur);
    uint2* bucket = (uint2*)(wsb + kOffBucket);

    zero_kernel<<<(kNUp + 255) / 256, 256, 0, stream>>>(cursor);

    constexpr int prep_blocks = kWFragN / 256 + (kE + 255) / 256;  // 72 + 331
    prep_kernel<<<prep_blocks, 256, 0, stream>>>(W, wfrag, row, col, val, cursor, bucket);

    // MEASUREMENT: launched twice (idempotent). dur_us - 76.3 == pool_gather cost.
    pool_gather<<<kNUp / 16 * kB, 256, 0, stream>>>(x, cursor, bucket, poolb);
    pool_gather<<<kNUp / 16 * kB, 256, 0, stream>>>(x, cursor, bucket, poolb);

    gemm_mfma<<<(kMRows / 16) / 4, 256, 0, stream>>>(poolb, wfrag, bias, indices, out);
}

// Round 11
// 78.423 us; speedup vs baseline: 1.2567x; 1.2567x over previous
//
#include <hip/hip_runtime.h>
#include <hip/hip_bf16.h>

// SpiralDeblock: B=8, N_IN=7056, N_UP=28224, SEQ=9, CIN=64, COUT=32
namespace {
constexpr int kB    = 8;
constexpr int kNIn  = 7056;
constexpr int kNUp  = 28224;
constexpr int kSeq  = 9;
constexpr int kCin  = 64;
constexpr int kCout = 32;
constexpr int kE    = 3 * kNUp;          // 84672
constexpr int kMRows = kB * kNUp;        // 225792
constexpr int kTilesPerB = kNUp / 16;    // 1764 (exact -> 16-row tiles never straddle batches)
constexpr int kWFragN = 18 * 2 * 64 * 8; // 18432 bf16 values (36,864 B)
constexpr int kCap   = 24;               // bucket capacity; P(overflow) ~ 6e-10 at Poisson(3)
constexpr int kGemmGrid = kMRows / 16 / 16;  // 882 blocks (16 M-tiles per block)

// ws layout (bytes), 16B-aligned
constexpr size_t kOffPool   = 0;                          // bf16 pooled: 28,901,376
constexpr size_t kOffWfrag  = 28901376;                   // 36,864
constexpr size_t kOffCur    = kOffWfrag + 36864;          // 112,896
constexpr size_t kOffBucket = kOffCur + 112896;           // N_UP*24*8 = 5,419,008
}

typedef __attribute__((ext_vector_type(8))) short short8;
typedef __attribute__((ext_vector_type(4))) float f32x4;

__device__ __forceinline__ unsigned short f32_to_bf16(float f) {  // RNE
    unsigned int u = __float_as_uint(f);
    u += 0x7fffu + ((u >> 16) & 1u);
    return (unsigned short)(u >> 16);
}

// --- zero cursor (graph-safe, ~1 us) --------------------------------------
__global__ __launch_bounds__(256) void zero_kernel(int* __restrict__ cursor) {
    int i = blockIdx.x * 256 + threadIdx.x;
    if (i < kNUp) cursor[i] = 0;
}

// --- merged prep: blocks [0,72) transpose W to fragment order; blocks [72,...) bucket edges
__global__ __launch_bounds__(256) void prep_kernel(const float* __restrict__ W,
                                                   unsigned short* __restrict__ wfrag,
                                                   const int* __restrict__ row,
                                                   const int* __restrict__ col,
                                                   const float* __restrict__ val,
                                                   int* __restrict__ cursor,
                                                   uint2* __restrict__ bucket) {
    int bid = blockIdx.x;
    if (bid < kWFragN / 256) {
        int i  = bid * 256 + threadIdx.x;
        int j  = i & 7;
        int l  = (i >> 3) & 63;
        int ct = (i >> 9) & 1;
        int ks = i >> 10;                            // 0..17
        int k  = ks * 32 + (l >> 4) * 8 + j;
        int o  = ct * 16 + (l & 15);
        wfrag[i] = f32_to_bf16(W[k * kCout + o]);
    } else {
        int e = (bid - kWFragN / 256) * 256 + threadIdx.x;
        if (e >= kE) return;
        int r = row[e];
        int slot = atomicAdd(&cursor[r], 1);
        if ((unsigned)slot < (unsigned)kCap)
            bucket[(size_t)r * kCap + slot] = make_uint2((unsigned)col[e], __float_as_uint(val[e]));
    }
}

// --- pooled[b,r,c] = sum_{edges of r} x[b,col,c]*val, stored bf16 ---------
// b = blockIdx&7: batch<->XCD affinity (one 1.8 MB x-slice per XCD L2).
// Measured round 10: 22.2 us.
__global__ __launch_bounds__(256) void pool_gather(const float* __restrict__ x,
                                                   const int* __restrict__ cursor,
                                                   const uint2* __restrict__ bucket,
                                                   unsigned short* __restrict__ poolb) {
    int t  = threadIdx.x;
    int c4 = t & 15;                                 // float4 chunk within row
    int b  = blockIdx.x & 7;                         // batch -> XCD (round-robin)
    int rb = blockIdx.x >> 3;                        // row-block 0..1763
    int r  = rb * 16 + (t >> 4);                     // < N_UP
    int n  = min(cursor[r], kCap);
    const uint2* bk = bucket + (size_t)r * kCap;
    const float* xb = x + (size_t)b * kNIn * kCin + (size_t)c4 * 4;

    f32x4 acc = {0.f, 0.f, 0.f, 0.f};

#pragma unroll
    for (int p = 0; p < 4; ++p) {                    // pairs (0,1),(2,3),(4,5),(6,7)
        if (2 * p < n) {
            uint4 q = *reinterpret_cast<const uint4*>(bk + 2 * p);
            unsigned c0 = min(q.x, (unsigned)(kNIn - 1));
            float    v0 = __uint_as_float(q.y);
            unsigned c1 = min(q.z, (unsigned)(kNIn - 1));
            float    v1 = (2 * p + 1 < n) ? __uint_as_float(q.w) : 0.f;
            f32x4 xv0 = *reinterpret_cast<const f32x4*>(xb + (size_t)c0 * kCin);
            f32x4 xv1 = *reinterpret_cast<const f32x4*>(xb + (size_t)c1 * kCin);
#pragma unroll
            for (int j = 0; j < 4; ++j)
                acc[j] = fmaf(xv1[j], v1, fmaf(xv0[j], v0, acc[j]));
        }
    }
    for (int k = 8; k < n; ++k) {                    // rare tail (P ~ 0.4%)
        uint2 ev = bk[k];
        float v = __uint_as_float(ev.y);
        f32x4 xv = *reinterpret_cast<const f32x4*>(xb + (size_t)ev.x * kCin);
#pragma unroll
        for (int j = 0; j < 4; ++j)
            acc[j] = fmaf(xv[j], v, acc[j]);
    }

    ushort4 o;
    o.x = f32_to_bf16(acc[0]);
    o.y = f32_to_bf16(acc[1]);
    o.z = f32_to_bf16(acc[2]);
    o.w = f32_to_bf16(acc[3]);
    *reinterpret_cast<ushort4*>(poolb + ((size_t)b * kNUp + r) * kCin + c4 * 4) = o;
}

// --- MFMA GEMM: out[R,o] = relu(sum_f spiral[R,f]*W[f,o] + bias[o]) -------
// 4 waves/block, FOUR 16-row M-tiles per wave (64 rows): per s the 4 B-fragments
// are read from LDS ONCE and feed 16 MFMAs (ds_read:MFMA = 1:4, was 1:1), and
// the LDS fill is amortized over 16 tiles (grid 3528 -> 882: wfrag traffic /4).
// A-fragments double-buffered one s ahead: 8 independent gathers prefetched
// under each 16-MFMA burst. All 36 idx loads hoisted before the barrier.
// Bijective XCD swizzle (882 % 8 != 0 -> m204 formula).
__global__ __launch_bounds__(256) void gemm_mfma(const unsigned short* __restrict__ poolb,
                                                 const unsigned short* __restrict__ wfrag,
                                                 const float* __restrict__ bias,
                                                 const int* __restrict__ indices,
                                                 float* __restrict__ out) {
    __shared__ short8 Bs[18 * 2 * 64];               // 2304 short8 = 36,864 B
    int t = threadIdx.x;
    const short8* wf = (const short8*)wfrag;
#pragma unroll
    for (int i = 0; i < 9; ++i)                      // coalesced b128 fill
        Bs[i * 256 + t] = wf[i * 256 + t];

    int l = t & 63;
    int w = t >> 6;
    int m  = l & 15;
    int kg = l >> 4;

    // bijective XCD swizzle for nwg=882: q=110, rem=2
    int bid = blockIdx.x;
    int xcd = bid & 7;                               // bid % 8
    int loc = bid >> 3;                              // bid / 8
    int wgid = (xcd < 2 ? xcd * 111 : 222 + (xcd - 2) * 110) + loc;

    int mbase = wgid * 16 + w * 4;                   // first of this wave's 4 M-tiles

    const unsigned short* pbp[4];
    int idxs[4][kSeq];
#pragma unroll
    for (int tt = 0; tt < 4; ++tt) {
        int mt = mbase + tt;
        int bb = mt / kTilesPerB;
        int n  = (mt - bb * kTilesPerB) * 16 + m;
        pbp[tt] = poolb + (size_t)bb * kNUp * kCin;
#pragma unroll
        for (int s = 0; s < kSeq; ++s) idxs[tt][s] = indices[n * kSeq + s];
    }
    float bs0 = bias[m];
    float bs1 = bias[16 + m];

    short8 A0[4], A1[4], N0[4], N1[4];
#pragma unroll
    for (int tt = 0; tt < 4; ++tt) {                 // prologue: s=0 fragments
        const short8* ar = (const short8*)(pbp[tt] + (size_t)idxs[tt][0] * kCin);
        A0[tt] = ar[kg];
        A1[tt] = ar[4 + kg];
    }

    f32x4 acc0[4], acc1[4];
#pragma unroll
    for (int tt = 0; tt < 4; ++tt) {
        acc0[tt] = (f32x4){0.f, 0.f, 0.f, 0.f};
        acc1[tt] = (f32x4){0.f, 0.f, 0.f, 0.f};
    }

    __syncthreads();                                 // Bs ready

#pragma unroll
    for (int s = 0; s < kSeq; ++s) {
        if (s < kSeq - 1) {                          // prefetch s+1 under the MFMA burst
#pragma unroll
            for (int tt = 0; tt < 4; ++tt) {
                const short8* ar = (const short8*)(pbp[tt] + (size_t)idxs[tt][s + 1] * kCin);
                N0[tt] = ar[kg];
                N1[tt] = ar[4 + kg];
            }
        }
        short8 b00 = Bs[(4 * s + 0) * 64 + l];
        short8 b01 = Bs[(4 * s + 1) * 64 + l];
        short8 b10 = Bs[(4 * s + 2) * 64 + l];
        short8 b11 = Bs[(4 * s + 3) * 64 + l];
#pragma unroll
        for (int tt = 0; tt < 4; ++tt) {
            acc0[tt] = __builtin_amdgcn_mfma_f32_16x16x32_bf16(A0[tt], b00, acc0[tt], 0, 0, 0);
            acc1[tt] = __builtin_amdgcn_mfma_f32_16x16x32_bf16(A0[tt], b01, acc1[tt], 0, 0, 0);
            acc0[tt] = __builtin_amdgcn_mfma_f32_16x16x32_bf16(A1[tt], b10, acc0[tt], 0, 0, 0);
            acc1[tt] = __builtin_amdgcn_mfma_f32_16x16x32_bf16(A1[tt], b11, acc1[tt], 0, 0, 0);
        }
#pragma unroll
        for (int tt = 0; tt < 4; ++tt) {             // rotate double buffer (renamed away)
            A0[tt] = N0[tt];
            A1[tt] = N1[tt];
        }
    }

#pragma unroll
    for (int tt = 0; tt < 4; ++tt) {
        int orow0 = (mbase + tt) * 16 + kg * 4;
#pragma unroll
        for (int r = 0; r < 4; ++r) {
            size_t orow = (size_t)(orow0 + r) * kCout;
            out[orow + m]      = fmaxf(acc0[tt][r] + bs0, 0.f);
            out[orow + 16 + m] = fmaxf(acc1[tt][r] + bs1, 0.f);
        }
    }
}

extern "C" void kernel_launch(void* const* d_in, const int* in_sizes, int n_in,
                              void* d_out, int out_size, void* d_ws, size_t ws_size,
                              hipStream_t stream) {
    const float* x    = (const float*)d_in[0];
    const float* val  = (const float*)d_in[1];
    const float* W    = (const float*)d_in[2];
    const float* bias = (const float*)d_in[3];
    const int* row     = (const int*)d_in[4];
    const int* col     = (const int*)d_in[5];
    const int* indices = (const int*)d_in[6];
    float* out = (float*)d_out;

    char* wsb = (char*)d_ws;
    unsigned short* poolb = (unsigned short*)(wsb + kOffPool);
    unsigned short* wfrag = (unsigned short*)(wsb + kOffWfrag);
    int* cursor  = (int*)(wsb + kOffCur);
    uint2* bucket = (uint2*)(wsb + kOffBucket);

    zero_kernel<<<(kNUp + 255) / 256, 256, 0, stream>>>(cursor);

    constexpr int prep_blocks = kWFragN / 256 + (kE + 255) / 256;  // 72 + 331
    prep_kernel<<<prep_blocks, 256, 0, stream>>>(W, wfrag, row, col, val, cursor, bucket);

    pool_gather<<<kNUp / 16 * kB, 256, 0, stream>>>(x, cursor, bucket, poolb);

    gemm_mfma<<<kGemmGrid, 256, 0, stream>>>(poolb, wfrag, bias, indices, out);
}